// Round 1
// baseline (81.318 us; speedup 1.0000x reference)
//
#include <hip/hip_runtime.h>
#include <cmath>

#define NV    8                 // variables
#define NM    42                // coefficients per variable (degree + p - 1)
#define NK    46                // knots per variable (degree + 2p)
#define TOT_C (NM * NV)         // 336
#define NRK   39                // distinct clamped k values: k-3 in [0, 39)
#define NRECS (NV * NRK)        // 312 records
#define REC_F 8                 // floats per record (32 B, aligned)
#define TPB   512               // threads per block
#define EPT   8                 // elements per thread (one full v-cycle)

typedef float f32x4 __attribute__((ext_vector_type(4)));

// ---------------------------------------------------------------------------
// Single fused kernel.
// Per-block prep (~2 KB of redundant work, amortized over 4096 elements):
//   incr = [raw[0], softplus(raw[1:])]; c = cumsum (Hillis-Steele, 6 rounds);
//   records rec[v*39+kk] = {c[kk..kk+3], q[kk..kk+2], 0} packed 32 B so the
//   per-element gather is two aligned ds_read_b128. Bank quad = (3v+kk)%4 is
//   uniform-random in kk -> balanced across all 32 banks (8 acc/bank floor).
// Main loop: 8 consecutive elements/thread => v == e is compile-time, so
//   t0/invd are scalar-loaded registers; x/y/ld move as float4.
// No workspace, no second launch.
// ---------------------------------------------------------------------------
__global__ __launch_bounds__(TPB) void fused_kernel(
        const float* __restrict__ x,
        const float* __restrict__ raw,
        const float* __restrict__ knots,
        float* __restrict__ y_out,
        float* __restrict__ ld_out,
        int total)
{
    __shared__ float s[TOT_C];
    __shared__ __align__(32) float rec[NRECS * REC_F];   // 9984 B

    int tid = threadIdx.x;

    // ---- incr = [raw0, softplus(raw[1:])] --------------------------------
    if (tid < TOT_C) {
        float r = raw[tid];
        float inc = (tid < NV) ? r
                  : ((r > 0.f) ? (r + log1pf(expf(-r))) : log1pf(expf(r)));
        s[tid] = inc;
    }
    __syncthreads();

    // ---- cumsum over j (rows of 8 vars), Hillis-Steele -------------------
    for (int off = 1; off < NM; off <<= 1) {
        float a = 0.f;
        if (tid < TOT_C) {
            int j = tid >> 3;
            a = s[tid] + ((j >= off) ? s[tid - off * NV] : 0.f);
        }
        __syncthreads();
        if (tid < TOT_C) s[tid] = a;
        __syncthreads();
    }

    // ---- build 32-B records: {c[kk..kk+3], q[kk..kk+2], 0} ---------------
    if (tid < NRECS) {
        int v  = tid / NRK;          // const-divide -> magic mul
        int kk = tid - v * NRK;
        float c0 = s[(kk + 0) * NV + v];
        float c1 = s[(kk + 1) * NV + v];
        float c2 = s[(kk + 2) * NV + v];
        float c3 = s[(kk + 3) * NV + v];
        // q[j] = 3*(c[j+1]-c[j]) / (t[j+4]-t[j+1]),  j = kk..kk+2  (max 44 < 46)
        float q0 = 3.f * (c1 - c0) / (knots[(kk + 4) * NV + v] - knots[(kk + 1) * NV + v]);
        float q1 = 3.f * (c2 - c1) / (knots[(kk + 5) * NV + v] - knots[(kk + 2) * NV + v]);
        float q2 = 3.f * (c3 - c2) / (knots[(kk + 6) * NV + v] - knots[(kk + 3) * NV + v]);
        f32x4 lo = {c0, c1, c2, c3};
        f32x4 hi = {q0, q1, q2, 0.f};
        f32x4* rp = (f32x4*)&rec[tid * REC_F];
        rp[0] = lo;
        rp[1] = hi;
    }
    __syncthreads();

    // ---- per-thread uniform tables (compile-time indexed => registers) ---
    float t0v[NV], invdv[NV];
    #pragma unroll
    for (int v = 0; v < NV; ++v) {
        float t0 = knots[v];                 // uniform -> s_load
        t0v[v]   = t0;
        invdv[v] = 1.f / (knots[NV + v] - t0);
    }

    const float k6 = 0.16666666666f;
    int i0 = (blockIdx.x * TPB + tid) * EPT;     // multiple of 8 => v == e

    if (i0 + EPT - 1 < total) {
        f32x4 xa = *(const f32x4*)(x + i0);
        f32x4 xb = *(const f32x4*)(x + i0 + 4);
        f32x4 ya, yb, la, lb;
        #pragma unroll
        for (int e = 0; e < EPT; ++e) {
            float xe = (e < 4) ? xa[e] : xb[e - 4];
            const int v = e;
            float f = (xe - t0v[v]) * invdv[v];
            int k = (int)floorf(f);
            k = min(max(k, 3), NK - 5);          // clip to [3, 41]
            float u = f - (float)k;              // extrapolates when clamped,
                                                 // same as deBoor
            const f32x4* rp = (const f32x4*)&rec[(v * NRK + (k - 3)) * REC_F];
            f32x4 cc = rp[0];                    // ds_read_b128
            f32x4 qq = rp[1];                    // ds_read_b128

            float omu = 1.f - u;
            float u2 = u * u,  o2 = omu * omu;
            float u3 = u2 * u, o3 = o2 * omu;
            float B0 = o3 * k6;
            float B3 = u3 * k6;
            float B1 = (3.f * u3 - 6.f * u2 + 4.f) * k6;
            float B2 = 1.f - B0 - B1 - B3;       // partition of unity
            float yv = fmaf(B0, cc.x, fmaf(B1, cc.y, fmaf(B2, cc.z, B3 * cc.w)));

            float w0 = 0.5f * o2, w2 = 0.5f * u2, w1 = 1.f - w0 - w2;
            float lv = __logf(fmaf(w0, qq.x, fmaf(w1, qq.y, w2 * qq.z)));

            if (e < 4) { ya[e] = yv; la[e] = lv; }
            else       { yb[e - 4] = yv; lb[e - 4] = lv; }
        }
        __builtin_nontemporal_store(ya, (f32x4*)(y_out + i0));
        __builtin_nontemporal_store(yb, (f32x4*)(y_out + i0 + 4));
        __builtin_nontemporal_store(la, (f32x4*)(ld_out + i0));
        __builtin_nontemporal_store(lb, (f32x4*)(ld_out + i0 + 4));
    } else {
        for (int i = i0; i < total; ++i) {
            int v = i & (NV - 1);
            float t0 = knots[v];
            float invd = 1.f / (knots[NV + v] - t0);
            float f = (x[i] - t0) * invd;
            int k = (int)floorf(f);
            k = min(max(k, 3), NK - 5);
            float u = f - (float)k;
            const float* rp = &rec[(v * NRK + (k - 3)) * REC_F];
            float c0 = rp[0], c1 = rp[1], c2 = rp[2], c3 = rp[3];
            float q0 = rp[4], q1 = rp[5], q2 = rp[6];
            float omu = 1.f - u;
            float u2 = u * u,  o2 = omu * omu;
            float u3 = u2 * u, o3 = o2 * omu;
            float B0 = o3 * k6;
            float B3 = u3 * k6;
            float B1 = (3.f * u3 - 6.f * u2 + 4.f) * k6;
            float B2 = 1.f - B0 - B1 - B3;
            y_out[i] = fmaf(B0, c0, fmaf(B1, c1, fmaf(B2, c2, B3 * c3)));
            float w0 = 0.5f * o2, w2 = 0.5f * u2, w1 = 1.f - w0 - w2;
            ld_out[i] = __logf(fmaf(w0, q0, fmaf(w1, q1, w2 * q2)));
        }
    }
}

extern "C" void kernel_launch(void* const* d_in, const int* in_sizes, int n_in,
                              void* d_out, int out_size, void* d_ws, size_t ws_size,
                              hipStream_t stream) {
    const float* x     = (const float*)d_in[0];
    const float* raw   = (const float*)d_in[1];
    const float* knots = (const float*)d_in[2];

    int total = in_sizes[0];             // N*V = 4,000,000
    float* y_out  = (float*)d_out;
    float* ld_out = y_out + total;

    int threads_needed = (total + EPT - 1) / EPT;
    int blocks = (threads_needed + TPB - 1) / TPB;
    fused_kernel<<<blocks, TPB, 0, stream>>>(x, raw, knots, y_out, ld_out, total);
}